// Round 3
// baseline (131.031 us; speedup 1.0000x reference)
//
#include <hip/hip_runtime.h>

// pred_vol (1,1,64,512,512) fp32; thresh 0.5; 9x9x9 max-pool NMS.
// Identity: thr is monotone and the window contains the center, so
// reference output == (c > 0.5 && c == max999_raw(x)) ? c : 0.
//
// v4: balanced two-pipe vertical + single barrier + distance-2 prefetch.
//  - Stage rows 0..8 of each plane via global_load_lds (18 segments).
//  - Vertical window rows hr..hr+5 from LDS (6 ds_read_b128), rows
//    hr+6..hr+8 straight from global (3 coalesced dwordx4, L1-hit) —
//    uniform per thread, so LDS(~864cy) and VMEM(~928cy) pipes overlap.
//  - vert(t) || horiz+emit(t-1) with dbuf bcol -> ONE barrier per step.
//  - braw triple-buffered; stage(t+2) issued AFTER vglob+cen so compiler's
//    counted vmcnt waits never drain the newest prefetch group.
static constexpr int Dd = 64;
static constexpr int Hh = 512;
static constexpr int Ww = 512;
static constexpr int RAD = 4;
static constexpr float THRESH_V = 0.5f;
static constexpr int W4 = Ww / 4;           // 128 float4 per row
static constexpr int PLANE4 = Hh * W4;      // 65536 float4 per D-plane

static constexpr int TH = 4;                // output h-rows per block
static constexpr int DC = 16;               // output d-planes per block
static constexpr int SROWS = 9;             // LDS-staged rows 0..8 (of 12-row window span)
static constexpr int NPL = DC + 2 * RAD;    // 24 planes touched per block
static constexpr int NBLK = (Hh / TH) * (Dd / DC);  // 512 blocks (2/CU)

typedef float nf4 __attribute__((ext_vector_type(4)));

__device__ __forceinline__ float4 f4max(float4 a, float4 b) {
    return make_float4(fmaxf(a.x, b.x), fmaxf(a.y, b.y), fmaxf(a.z, b.z), fmaxf(a.w, b.w));
}
__device__ __forceinline__ int iclamp(int v, int lo, int hi) {
    return v < lo ? lo : (v > hi ? hi : v);
}

// Barrier with counted vmcnt: drains this step's needed DMA group while the
// newest prefetch group (and output store) stay in flight. lgkmcnt(0) orders
// LDS only.
#define BAR_VM(N) asm volatile("s_waitcnt vmcnt(" #N ") lgkmcnt(0)\n\ts_barrier" ::: "memory")

// Direct global->LDS DMA, 16B per lane, dest = wave-uniform base + lane*16.
__device__ __forceinline__ void load_lds16(const float4* g, float4* l) {
    __builtin_amdgcn_global_load_lds(
        (const __attribute__((address_space(1))) void*)g,
        (__attribute__((address_space(3))) void*)l, 16, 0, 0);
}

// (512,2): min-blocks semantics -> 2 blocks/CU, 128-VGPR cap (proven good).
__global__ __launch_bounds__(512, 2)
void fused_nms_k4(const float4* __restrict__ x4, float4* __restrict__ o4) {
    // 3 x 9-row raw buffers (54 KB) + 2 x 4-row col-max buffers (16 KB) = 70 KB
    __shared__ float4 braw[3][SROWS * W4];
    __shared__ float4 bcol[2][TH * W4];

    const int tid  = threadIdx.x;
    const int w4   = tid & (W4 - 1);   // 0..127
    const int hr   = tid >> 7;         // 0..3 (output row within block)
    const int wid  = tid >> 6;         // wave 0..7
    const int lane = tid & 63;

    // XCD swizzle: band = blockIdx&7 -> h-band stays on one XCD's L2
    const int b    = blockIdx.x;
    const int band = b & 7;
    const int rest = b >> 3;           // 0..63
    const int ht   = band * 16 + (rest & 15);  // 0..127
    const int dc   = rest >> 4;        // 0..3
    const int h0   = ht * TH;
    const int d0   = dc * DC;

    const int colm = w4 ? w4 - 1 : 0;
    const int colp = (w4 < W4 - 1) ? w4 + 1 : W4 - 1;
    const int outrow = (h0 + hr) * W4 + w4;

    // DMA staging: 18 segments (9 rows x 2 half-rows); waves 0..7 take
    // segments {wid, wid+8}, waves 0..1 additionally {16+wid}.
    int goff[3], loff[3];
#pragma unroll
    for (int k = 0; k < 3; ++k) {
        const int s    = (k < 2) ? (wid + 8 * k) : (16 + wid);  // 0..17
        const int row  = s >> 1;               // 0..8
        const int half = s & 1;                // 0/1
        const int gh   = iclamp(h0 - RAD + row, 0, Hh - 1);
        goff[k] = gh * W4 + half * 64 + lane;
        loff[k] = row * W4 + half * 64;
    }

    // Global-side vertical rows: window rows hr+6..hr+8 (span rows 6..11).
    int ghoff[3];
#pragma unroll
    for (int i = 0; i < 3; ++i) {
        const int gh = iclamp(h0 - RAD + hr + 6 + i, 0, Hh - 1);
        ghoff[i] = gh * W4 + w4;
    }

    auto stage = [&](int p) {  // stage plane index p into braw[p % 3]
        const int gd = iclamp(d0 - RAD + p, 0, Dd - 1);
        const float4* pl = x4 + (size_t)gd * PLANE4;
        float4* dst = braw[p % 3];
        load_lds16(pl + goff[0], dst + loff[0]);
        load_lds16(pl + goff[1], dst + loff[1]);
        if (wid < 2) load_lds16(pl + goff[2], dst + loff[2]);
    };

    // Ring of HW-maxed planes; R[(t-1)&7] written after use at step t.
    float4 R[8];
    float4 vprev;   // own column's vertical max from the previous step

    // Prologue: planes 0 and 1 staged (in-loop stage covers 2..23).
    stage(0);
    stage(1);

    // 25 steps, fully unrolled (all t-conditions constant-fold).
#pragma unroll
    for (int t = 0; t <= NPL; ++t) {
        const bool doV   = (t <= NPL - 1);     // vertical for plane t (0..23)
        const bool doDMA = (t <= NPL - 3);     // stage plane t+2 (2..23)
        const bool doH   = (t >= 1);           // horiz+ring for plane t-1
        const bool doE   = (t >= 9);           // emit output plane d0 + t - 9

        // ---- top barrier: publishes bcol(t-1), guarantees braw plane t.
        // Outstanding allowed: stage(t+1) group (2) [+ store(t-1) (1) from
        // t=10 on]. Conservative-safe for the wid<2 3-segment waves.
        if (t <= 9)       { BAR_VM(2); }
        else if (t <= 22) { BAR_VM(3); }
        else              { BAR_VM(1); }

        // ---- (a) issue global vertical rows for plane t (oldest group,
        //          so its wait never drains cen/stage below).
        float4 g0, g1, g2;
        if (doV) {
            const int gd = iclamp(d0 - RAD + t, 0, Dd - 1);
            const float4* pl = x4 + (size_t)gd * PLANE4;
            g0 = pl[ghoff[0]];
            g1 = pl[ghoff[1]];
            g2 = pl[ghoff[2]];
        }
        __builtin_amdgcn_sched_barrier(0);
        // ---- (b) issue center load for the emitted plane.
        float4 cen;
        if (doE) cen = x4[(size_t)(d0 + t - 9) * PLANE4 + outrow];
        __builtin_amdgcn_sched_barrier(0);
        // ---- (c) issue distance-2 DMA prefetch (newest VMEM group: stays
        //          in flight across this and the next step).
        if (doDMA) stage(t + 2);
        __builtin_amdgcn_sched_barrier(0);

        // ---- (d) vertical: 6 LDS rows (hr..hr+5) + 3 global rows folded.
        float4 vown;
        if (doV) {
            const float4* Bc = &braw[t % 3][hr * W4 + w4];
            float4 m01 = f4max(Bc[0 * W4], Bc[1 * W4]);
            float4 m23 = f4max(Bc[2 * W4], Bc[3 * W4]);
            float4 m45 = f4max(Bc[4 * W4], Bc[5 * W4]);
            float4 mg  = f4max(f4max(g0, g1), g2);   // compiler: vmcnt leaves cen+stage
            vown = f4max(f4max(m01, m23), f4max(m45, mg));
            bcol[t & 1][hr * W4 + w4] = vown;
        }

        // ---- (e) horizontal 9-window + D-ring + emit for plane t-1.
        if (doH) {
            const float4* Bp = &bcol[(t - 1) & 1][hr * W4];
            const float4 lm = Bp[colm];
            const float4 rm = Bp[colp];
            const float4 cm = vprev;
            const float l3 = lm.w, l2 = fmaxf(lm.z, l3), l1 = fmaxf(lm.y, l2), l0 = fmaxf(lm.x, l1);
            const float core = fmaxf(fmaxf(cm.x, cm.y), fmaxf(cm.z, cm.w));
            const float r0 = rm.x, r1 = fmaxf(r0, rm.y), r2 = fmaxf(r1, rm.z), r3 = fmaxf(r2, rm.w);
            float4 pm;
            pm.x = fmaxf(l0, fmaxf(core, r0));
            pm.y = fmaxf(l1, fmaxf(core, r1));
            pm.z = fmaxf(l2, fmaxf(core, r2));
            pm.w = fmaxf(l3, fmaxf(core, r3));

            if (doE) {
                float4 mm = pm;
#pragma unroll
                for (int i = 0; i < 8; ++i) mm = f4max(mm, R[i]);
                nf4 q;
                q.x = (cen.x > THRESH_V && cen.x == mm.x) ? cen.x : 0.0f;
                q.y = (cen.y > THRESH_V && cen.y == mm.y) ? cen.y : 0.0f;
                q.z = (cen.z > THRESH_V && cen.z == mm.z) ? cen.z : 0.0f;
                q.w = (cen.w > THRESH_V && cen.w == mm.w) ? cen.w : 0.0f;
                __builtin_nontemporal_store(
                    q, (nf4*)&o4[(size_t)(d0 + t - 9) * PLANE4 + outrow]);
            }
            R[(t - 1) & 7] = pm;  // overwrite after use
        }

        if (doV) vprev = vown;
    }
}

extern "C" void kernel_launch(void* const* d_in, const int* in_sizes, int n_in,
                              void* d_out, int out_size, void* d_ws, size_t ws_size,
                              hipStream_t stream) {
    const float4* x4 = (const float4*)d_in[0];
    float4* out4 = (float4*)d_out;
    (void)d_ws; (void)ws_size; (void)in_sizes; (void)n_in; (void)out_size;
    fused_nms_k4<<<dim3(NBLK), dim3(512), 0, stream>>>(x4, out4);
}

// Round 4
// 114.853 us; speedup vs baseline: 1.1409x; 1.1409x over previous
//
#include <hip/hip_runtime.h>

// pred_vol (1,1,64,512,512) fp32; thresh 0.5; 9x9x9 max-pool NMS.
// Identity: thr is monotone and the window contains the center, so
// reference output == (c > 0.5 && c == max999_raw(x)) ? c : 0.
//
// v5 = v2 (proven 48us skeleton: DMA-staged raw rows, per-thread vertical
// 9-max from LDS, bcol + prefix/suffix horizontal, 8-slot D-ring) plus two
// pipeline-only changes:
//  - braw TRIPLE-buffered, DMA prefetch distance 2 (plane t staged at t-2,
//    ~2 steps in flight >> HBM latency) with exact counted-vmcnt barriers.
//  - center value captured from the vertical's own Bc[4*W4] read into a
//    4-deep register ring C[] (read at t, overwritten at t) instead of a
//    same-step global re-load. -8 VMEM insts/plane, no exposed load latency.
static constexpr int Dd = 64;
static constexpr int Hh = 512;
static constexpr int Ww = 512;
static constexpr int RAD = 4;
static constexpr float THRESH_V = 0.5f;
static constexpr int W4 = Ww / 4;           // 128 float4 per row
static constexpr int PLANE4 = Hh * W4;      // 65536 float4 per D-plane

static constexpr int TH = 4;                // output h-rows per block
static constexpr int DC = 16;               // output d-planes per block
static constexpr int ROWS = TH + 2 * RAD;   // 12 staged raw rows per plane
static constexpr int NPL = DC + 2 * RAD;    // 24 d-steps per block
static constexpr int NBLK = (Hh / TH) * (Dd / DC);  // 512 blocks (2/CU)

typedef float nf4 __attribute__((ext_vector_type(4)));

__device__ __forceinline__ float4 f4max(float4 a, float4 b) {
    return make_float4(fmaxf(a.x, b.x), fmaxf(a.y, b.y), fmaxf(a.z, b.z), fmaxf(a.w, b.w));
}
__device__ __forceinline__ int iclamp(int v, int lo, int hi) {
    return v < lo ? lo : (v > hi ? hi : v);
}

// Counted-vmcnt barrier: drains this wave's stage(t) DMA group while newer
// prefetch groups and output stores stay in flight. lgkmcnt(0) orders LDS.
#define BAR_VM(N) asm volatile("s_waitcnt vmcnt(" #N ") lgkmcnt(0)\n\ts_barrier" ::: "memory")
// LDS-only barrier: publishes bcol writes without touching VMEM counters.
#define BAR_LDS() asm volatile("s_waitcnt lgkmcnt(0)\n\ts_barrier" ::: "memory")

// Direct global->LDS DMA, 16B per lane, dest = wave-uniform base + lane*16.
__device__ __forceinline__ void load_lds16(const float4* g, float4* l) {
    __builtin_amdgcn_global_load_lds(
        (const __attribute__((address_space(1))) void*)g,
        (__attribute__((address_space(3))) void*)l, 16, 0, 0);
}

// (512,2): min-blocks semantics -> 2 blocks/CU, 128-VGPR cap (proven good).
__global__ __launch_bounds__(512, 2)
void fused_nms_k5(const float4* __restrict__ x4, float4* __restrict__ o4) {
    // 3 x 12-row raw buffers (72 KB) + 4-row col-max buffer (8 KB) = 80 KB,
    // exactly 2 blocks/CU on the 160 KB pool.
    __shared__ float4 braw[3][ROWS * W4];
    __shared__ float4 bcol[TH * W4];

    const int tid  = threadIdx.x;
    const int w4   = tid & (W4 - 1);   // 0..127
    const int hr   = tid >> 7;         // 0..3 (output row within block)
    const int wid  = tid >> 6;         // wave 0..7
    const int lane = tid & 63;

    // XCD swizzle: band = blockIdx&7 -> h-band of 64 rows stays on one XCD's L2
    const int b    = blockIdx.x;
    const int band = b & 7;
    const int rest = b >> 3;           // 0..63
    const int ht   = band * 16 + (rest & 15);  // 0..127
    const int dc   = rest >> 4;        // 0..3
    const int h0   = ht * TH;
    const int d0   = dc * DC;

    const int colm = w4 ? w4 - 1 : 0;
    const int colp = (w4 < W4 - 1) ? w4 + 1 : W4 - 1;
    const int outrow = (h0 + hr) * W4 + w4;

    // Staging descriptors: 24 segments (12 rows x 2 half-rows), 3 per wave.
    int goff[3], loff[3];
#pragma unroll
    for (int k = 0; k < 3; ++k) {
        const int s    = wid + 8 * k;          // 0..23
        const int row  = s >> 1;               // 0..11
        const int half = s & 1;                // 0/1
        const int gh   = iclamp(h0 - RAD + row, 0, Hh - 1);
        goff[k] = gh * W4 + half * 64 + lane;
        loff[k] = row * W4 + half * 64;
    }

    auto stage = [&](int p) {  // stage plane index p into braw[p % 3]
        const int gd = iclamp(d0 - RAD + p, 0, Dd - 1);
        const float4* pl = x4 + (size_t)gd * PLANE4;
        float4* dst = braw[p % 3];
#pragma unroll
        for (int k = 0; k < 3; ++k)
            load_lds16(pl + goff[k], dst + loff[k]);
    };

    // R: 8-slot ring of fully HxW-maxed plane rows (window planes t-8..t-1).
    // C: 4-slot ring of raw center values (written step t, read step t+4;
    //    read-before-overwrite within the same step).
    float4 R[8];
    float4 C[4];

    // Prologue: planes 0,1 staged; in-loop stage(t+2) covers 2..23.
    stage(0);
    stage(1);

    // 24 steps, fully unrolled: all parities/slots/vmcnt counts are static.
#pragma unroll
    for (int t = 0; t < NPL; ++t) {
        const bool doE = (t >= 8);   // emit output plane d0 + t - 8

        // Top barrier: guarantee stage(t) drained. Per-wave issue stream after
        // stage(t) [issued at step t-2]: store(t-2) [t>=10], stage(t+1) x3
        // [t<=22], store(t-1) [t>=9]  ->  N = 3*[t<=22] + [t>=10] + [t>=9].
        if (t <= 8)       { BAR_VM(3); }
        else if (t == 9)  { BAR_VM(4); }
        else if (t <= 22) { BAR_VM(5); }
        else              { BAR_VM(2); }

        // Distance-2 prefetch: in flight for ~2 full steps.
        if (t + 2 < NPL) stage(t + 2);
        __builtin_amdgcn_sched_barrier(0);

        // Vertical 9-window max at own column (rows hr..hr+8 of the 12-row
        // span). Bc[4*W4] is the raw center (global row h0+hr, plane
        // clamp(d0-4+t) — exact for every emitted plane).
        const float4* Bc = &braw[t % 3][hr * W4 + w4];
        float4 q0 = Bc[0 * W4], q1 = Bc[1 * W4], q2 = Bc[2 * W4], q3 = Bc[3 * W4];
        float4 c4 = Bc[4 * W4];
        float4 q5 = Bc[5 * W4], q6 = Bc[6 * W4], q7 = Bc[7 * W4], q8 = Bc[8 * W4];
        float4 m = f4max(f4max(f4max(q0, q1), f4max(q2, q3)),
                         f4max(f4max(c4, q5), f4max(f4max(q6, q7), q8)));
        bcol[hr * W4 + w4] = m;
        BAR_LDS();

        // Horizontal 9-window via prefix/suffix from neighbor col-maxes.
        const float4 lm = bcol[hr * W4 + colm];
        const float4 rm = bcol[hr * W4 + colp];
        const float l3 = lm.w, l2 = fmaxf(lm.z, l3), l1 = fmaxf(lm.y, l2), l0 = fmaxf(lm.x, l1);
        const float core = fmaxf(fmaxf(m.x, m.y), fmaxf(m.z, m.w));
        const float r0 = rm.x, r1 = fmaxf(r0, rm.y), r2 = fmaxf(r1, rm.z), r3 = fmaxf(r2, rm.w);
        float4 pm;
        pm.x = fmaxf(l0, fmaxf(core, r0));
        pm.y = fmaxf(l1, fmaxf(core, r1));
        pm.z = fmaxf(l2, fmaxf(core, r2));
        pm.w = fmaxf(l3, fmaxf(core, r3));

        // Emit: D-window-9 = max(8 ring slots, current pm); center from C.
        if (doE) {
            const float4 cen = C[t & 3];   // written at step t-4 (plane d0+t-8)
            float4 mm = pm;
#pragma unroll
            for (int i = 0; i < 8; ++i) mm = f4max(mm, R[i]);
            nf4 q;
            q.x = (cen.x > THRESH_V && cen.x == mm.x) ? cen.x : 0.0f;
            q.y = (cen.y > THRESH_V && cen.y == mm.y) ? cen.y : 0.0f;
            q.z = (cen.z > THRESH_V && cen.z == mm.z) ? cen.z : 0.0f;
            q.w = (cen.w > THRESH_V && cen.w == mm.w) ? cen.w : 0.0f;
            __builtin_nontemporal_store(
                q, (nf4*)&o4[(size_t)(d0 + t - 8) * PLANE4 + outrow]);
        }
        R[t & 7] = pm;   // overwrite after use
        C[t & 3] = c4;   // overwrite after read
    }
}

extern "C" void kernel_launch(void* const* d_in, const int* in_sizes, int n_in,
                              void* d_out, int out_size, void* d_ws, size_t ws_size,
                              hipStream_t stream) {
    const float4* x4 = (const float4*)d_in[0];
    float4* out4 = (float4*)d_out;
    (void)d_ws; (void)ws_size; (void)in_sizes; (void)n_in; (void)out_size;
    fused_nms_k5<<<dim3(NBLK), dim3(512), 0, stream>>>(x4, out4);
}